// Round 10
// baseline (196.510 us; speedup 1.0000x reference)
//
#include <hip/hip_runtime.h>
#include <hip/hip_bf16.h>

typedef __attribute__((ext_vector_type(4))) float f32x4;
typedef __attribute__((ext_vector_type(16))) float f32x16;
typedef __attribute__((ext_vector_type(8))) short bf16x8;
typedef __attribute__((ext_vector_type(4))) unsigned int u32x4;
typedef unsigned short u16;

#define DEV static __device__ __forceinline__

DEV u16 f2bf(float f) {
    union { float f; unsigned int u; } v; v.f = f;
    unsigned int r = v.u + 0x7FFFu + ((v.u >> 16) & 1u);
    return (u16)(r >> 16);
}

DEV unsigned int cvt_pk(float lo, float hi) {
    unsigned int r;
    asm("v_cvt_pk_bf16_f32 %0, %1, %2" : "=v"(r) : "v"(lo), "v"(hi));
    return r;
}

// v_permlane32_swap_b32 a, b: a[32..63] <-> b[0..31]
DEV void pswap(unsigned int& a, unsigned int& b) {
    asm volatile("v_permlane32_swap_b32 %0, %1" : "+v"(a), "+v"(b));
}

DEV void async16(const void* g, void* l) {
    __builtin_amdgcn_global_load_lds((const __attribute__((address_space(1))) unsigned int*)g,
                                     (__attribute__((address_space(3))) unsigned int*)l, 16, 0, 0);
}

// ---------------- fused f32 -> bf16 convert + exp-mask precompute ----------------
__global__ void cvt_all(const float4* __restrict__ x, const float4* __restrict__ wq,
                        const float4* __restrict__ wk, const float4* __restrict__ wv,
                        ushort4* __restrict__ xb, ushort4* __restrict__ wb,
                        const float* __restrict__ mask, float* __restrict__ em) {
    int bid = blockIdx.x;
    if (bid >= 11264) {
        int i = (bid - 11264) * 256 + threadIdx.x;
        em[i] = __builtin_amdgcn_exp2f(mask[i] * 1.44269504088896340736f);
        return;
    }
    const float4* s;
    ushort4* d;
    int i;
    if (bid < 8192) {
        s = x; d = xb; i = bid * 256 + threadIdx.x;
    } else {
        int r = bid - 8192;
        int wsel = r >> 10;
        s = (wsel == 0) ? wq : (wsel == 1) ? wk : wv;
        d = wb + (size_t)wsel * 262144;
        i = (r & 1023) * 256 + threadIdx.x;
    }
    float4 v = s[i];
    ushort4 o;
    o.x = f2bf(v.x); o.y = f2bf(v.y); o.z = f2bf(v.z); o.w = f2bf(v.w);
    d[i] = o;
}

// ---------------- QKV projection GEMM (double-buffered, prefetch, 1 barrier/iter) ----------------
// p=0 -> Q scaled by 0.125*log2e, [B,H,S,64]; p=1 -> K [B,H,S,64];
// p=2 -> V transposed [B,H,64,S], pre-scaled by em[b,s]
__launch_bounds__(256, 2)
__global__ void qkv_gemm(const u16* __restrict__ xb, const u16* __restrict__ wb,
                         const float* __restrict__ bq, const float* __restrict__ bk,
                         const float* __restrict__ bv, const float* __restrict__ em,
                         u16* __restrict__ Qb, u16* __restrict__ Kb, u16* __restrict__ Vtb) {
    __shared__ u16 Al[2][128 * 64];
    __shared__ u16 Bl[2][128 * 64];
    const int t = threadIdx.x, ln = t & 63, w = t >> 6;
    const int wr = w >> 1, wc = w & 1;
    const int m0 = blockIdx.x * 128, e0 = blockIdx.y * 128, p = blockIdx.z;
    const u16* Wp = wb + (size_t)p * 1048576;
    const float* bias = (p == 0) ? bq : (p == 1) ? bk : bv;

    const int srow = t >> 3, scol = (t & 7) * 8;

    f32x4 acc[4][4];
#pragma unroll
    for (int i = 0; i < 4; i++)
#pragma unroll
        for (int j = 0; j < 4; j++) acc[i][j] = (f32x4){0.f, 0.f, 0.f, 0.f};

#define G_STAGE(buf, kk)                                                              \
    {                                                                                 \
        _Pragma("unroll")                                                             \
        for (int c = 0; c < 4; c++) {                                                 \
            int r = c * 32 + srow;                                                    \
            async16(&xb[(size_t)(m0 + r) * 1024 + (kk) + scol], &Al[buf][r * 64 + scol]); \
            async16(&Wp[(size_t)(e0 + r) * 1024 + (kk) + scol], &Bl[buf][r * 64 + scol]); \
        }                                                                             \
    }

    G_STAGE(0, 0);
    __syncthreads();
    int cur = 0;
    for (int kt = 0; kt < 16; kt++) {
        if (kt < 15) G_STAGE(cur ^ 1, (kt + 1) * 64);
#pragma unroll
        for (int kc = 0; kc < 2; kc++) {
            bf16x8 a[4], bb[4];
#pragma unroll
            for (int mf = 0; mf < 4; mf++)
                a[mf] = *(const bf16x8*)&Al[cur][(wr * 64 + mf * 16 + (ln & 15)) * 64 + kc * 32 + (ln >> 4) * 8];
#pragma unroll
            for (int nf = 0; nf < 4; nf++)
                bb[nf] = *(const bf16x8*)&Bl[cur][(wc * 64 + nf * 16 + (ln & 15)) * 64 + kc * 32 + (ln >> 4) * 8];
            __builtin_amdgcn_s_setprio(1);
#pragma unroll
            for (int mf = 0; mf < 4; mf++)
#pragma unroll
                for (int nf = 0; nf < 4; nf++)
                    acc[mf][nf] = __builtin_amdgcn_mfma_f32_16x16x32_bf16(a[mf], bb[nf], acc[mf][nf], 0, 0, 0);
            __builtin_amdgcn_s_setprio(0);
        }
        __syncthreads();
        cur ^= 1;
    }
#undef G_STAGE

    const int q16 = ln & 15, g = ln >> 4;
    if (p == 2) {
#pragma unroll
        for (int nf = 0; nf < 4; nf++) {
            int e = e0 + wc * 64 + nf * 16 + q16;
            float bias_v = bias[e];
            int h = e >> 6, hd = e & 63;
#pragma unroll
            for (int mf = 0; mf < 4; mf++) {
                int m = m0 + wr * 64 + mf * 16 + g * 4;
                int b = m >> 11, s = m & 2047;
                f32x4 emv = *(const f32x4*)&em[b * 2048 + s];
                ushort4 pk;
                pk.x = f2bf((acc[mf][nf][0] + bias_v) * emv[0]);
                pk.y = f2bf((acc[mf][nf][1] + bias_v) * emv[1]);
                pk.z = f2bf((acc[mf][nf][2] + bias_v) * emv[2]);
                pk.w = f2bf((acc[mf][nf][3] + bias_v) * emv[3]);
                *(ushort4*)&Vtb[((size_t)((b * 16 + h) * 64 + hd)) * 2048 + s] = pk;
            }
        }
    } else {
        const float qscale = (p == 0) ? 0.18033688011112042f : 1.0f;
        u16* out = (p == 0) ? Qb : Kb;
#pragma unroll
        for (int nf = 0; nf < 4; nf++) {
            int e = e0 + wc * 64 + nf * 16 + q16;
            float bias_v = bias[e];
            int h = e >> 6, hd = e & 63;
#pragma unroll
            for (int mf = 0; mf < 4; mf++) {
#pragma unroll
                for (int r = 0; r < 4; r++) {
                    int m = m0 + wr * 64 + mf * 16 + g * 4 + r;
                    int b = m >> 11, s = m & 2047;
                    out[((size_t)(b * 16 + h) * 2048 + s) * 64 + hd] = f2bf((acc[mf][nf][r] + bias_v) * qscale);
                }
            }
        }
    }
}

// ---------------- fused flash attention (32x32x16 MFMA, in-register P, high-occupancy) ----------------
// 128-thr blocks (2 waves x 32 q); single-buffered K/V (16KB LDS); grid 2048 -> 8 blocks/CU,
// 16 waves/CU: cross-block TLP covers staging latency and exp/MFMA phase gaps.
__launch_bounds__(128, 3)
__global__ void attn_kernel(const u16* __restrict__ Q, const u16* __restrict__ K,
                            const u16* __restrict__ Vt, const float* __restrict__ em,
                            float* __restrict__ out) {
    __shared__ u16 Kl[64 * 64];
    __shared__ u16 Vl[64 * 64];
    const int t = threadIdx.x, ln = t & 63, w = t >> 6;   // w in {0,1}
    const int ln31 = ln & 31, hi = ln >> 5, ln7 = ln & 7;

    // bijective XCD swizzle: 2048 blocks = 8 XCDs x 256 (8 bh x 32 qbi per XCD)
    const int bid0 = blockIdx.x;
    const int swz = (bid0 & 7) * 256 + (bid0 >> 3);
    const int qbi = swz & 31, bh = swz >> 5;
    const int b = bh >> 4, h = bh & 15;
    const int qr = qbi * 64 + w * 32;
    const size_t base = (size_t)bh * 2048 * 64;

    // Q fragments (B-operand of S^T = K·Q^T, 32x32x16): col=q=ln31, k(d)=hi*8+j
    bf16x8 aq[4];
#pragma unroll
    for (int ds = 0; ds < 4; ds++)
        aq[ds] = *(const bf16x8*)&Q[base + (size_t)(qr + ln31) * 64 + ds * 16 + hi * 8];

    // staging: linear LDS dest, pre-swizzled global chunk (chunk c stored at c^(row&7))
    const int rbase = t >> 3;
    const int sc = (t & 7) ^ (rbase & 7);

#define A_STAGE(kk)                                                                        \
    {                                                                                      \
        _Pragma("unroll")                                                                  \
        for (int i = 0; i < 4; i++) {                                                      \
            int row = i * 16 + rbase;                                                      \
            async16(&K[base + (size_t)((kk) + row) * 64 + sc * 8], &Kl[(i * 128 + t) * 8]); \
            async16(&Vt[base + (size_t)row * 2048 + (kk) + sc * 8], &Vl[(i * 128 + t) * 8]); \
        }                                                                                  \
    }

    f32x16 accT[2];   // [d-tile dt]; lane: q=ln31, d=dt*32+(r&3)+8*(r>>2)+4*hi
    accT[0] = (f32x16){};
    accT[1] = (f32x16){};
    f32x4 lacc = (f32x4){0.f, 0.f, 0.f, 0.f};

    for (int kt = 0; kt < 32; kt++) {
        const int k0 = kt * 64;
        if (kt) __syncthreads();   // WAR: previous tile's reads complete
        A_STAGE(k0);
        __syncthreads();           // staged data visible (vmcnt(0) drain; other blocks cover)

#pragma unroll
        for (int kti = 0; kti < 2; kti++) {
            // K fragments (A-operand): row k = kti*32+ln31, d = ds*16+hi*8+j
            bf16x8 ka[4];
#pragma unroll
            for (int ds = 0; ds < 4; ds++)
                ka[ds] = *(const bf16x8*)&Kl[(kti * 32 + ln31) * 64 + (((ds << 1) | hi) ^ ln7) * 8];

            // em for this lane's k rows: k = kti*32 + 8*rf + 4*hi + {0..3}
            f32x4 em4[4];
#pragma unroll
            for (int rf = 0; rf < 4; rf++)
                em4[rf] = *(const f32x4*)&em[b * 2048 + k0 + kti * 32 + rf * 8 + hi * 4];

            f32x16 z = (f32x16){};
            __builtin_amdgcn_s_setprio(1);
#pragma unroll
            for (int ds = 0; ds < 4; ds++)
                z = __builtin_amdgcn_mfma_f32_32x32x16_bf16(ka[ds], aq[ds], z, 0, 0, 0);
            __builtin_amdgcn_s_setprio(0);

            // p = exp2(score); Q pre-scaled so z is already in exp2 domain
            float p[16];
#pragma unroll
            for (int i = 0; i < 16; i++) p[i] = __builtin_amdgcn_exp2f(z[i]);

#pragma unroll
            for (int rf = 0; rf < 4; rf++) {
                lacc[0] += p[4 * rf + 0] * em4[rf][0];
                lacc[1] += p[4 * rf + 1] * em4[rf][1];
                lacc[2] += p[4 * rf + 2] * em4[rf][2];
                lacc[3] += p[4 * rf + 3] * em4[rf][3];
            }

            // pack to bf16 pairs, redistribute across hi-halves (B-frag k = s*16+hi*8+j)
            unsigned int pk00 = cvt_pk(p[0], p[1]),   pk01 = cvt_pk(p[2], p[3]);
            unsigned int pk10 = cvt_pk(p[4], p[5]),   pk11 = cvt_pk(p[6], p[7]);
            unsigned int pk20 = cvt_pk(p[8], p[9]),   pk21 = cvt_pk(p[10], p[11]);
            unsigned int pk30 = cvt_pk(p[12], p[13]), pk31 = cvt_pk(p[14], p[15]);
            pswap(pk00, pk10); pswap(pk01, pk11);   // k-step s=0
            pswap(pk20, pk30); pswap(pk21, pk31);   // k-step s=1
            u32x4 pb[2];
            pb[0][0] = pk00; pb[0][1] = pk01; pb[0][2] = pk10; pb[0][3] = pk11;
            pb[1][0] = pk20; pb[1][1] = pk21; pb[1][2] = pk30; pb[1][3] = pk31;

            // ctx^T += V'^T · P^T  (V' pre-scaled by em)
            __builtin_amdgcn_s_setprio(1);
#pragma unroll
            for (int s = 0; s < 2; s++) {
                bf16x8 pv = *(const bf16x8*)&pb[s];
#pragma unroll
                for (int dt = 0; dt < 2; dt++) {
                    bf16x8 va = *(const bf16x8*)&Vl[(dt * 32 + ln31) * 64 +
                                                    ((kti * 4 + s * 2 + hi) ^ ln7) * 8];
                    accT[dt] = __builtin_amdgcn_mfma_f32_32x32x16_bf16(va, pv, accT[dt], 0, 0, 0);
                }
            }
            __builtin_amdgcn_s_setprio(0);
        }
    }
#undef A_STAGE

    // epilogue: l = own partial + partner half, then scaled f32x4 stores
    float l = (lacc[0] + lacc[1]) + (lacc[2] + lacc[3]);
    l += __shfl_xor(l, 32);
    float inv = 1.0f / l;
    int q = qr + ln31;
#pragma unroll
    for (int dt = 0; dt < 2; dt++) {
#pragma unroll
        for (int rf = 0; rf < 4; rf++) {
            f32x4 o;
            o[0] = accT[dt][4 * rf + 0] * inv;
            o[1] = accT[dt][4 * rf + 1] * inv;
            o[2] = accT[dt][4 * rf + 2] * inv;
            o[3] = accT[dt][4 * rf + 3] * inv;
            *(f32x4*)&out[((size_t)(b * 2048 + q)) * 1024 + h * 64 + dt * 32 + rf * 8 + hi * 4] = o;
        }
    }
}

extern "C" void kernel_launch(void* const* d_in, const int* in_sizes, int n_in,
                              void* d_out, int out_size, void* d_ws, size_t ws_size,
                              hipStream_t stream) {
    const float* x    = (const float*)d_in[0];
    const float* mask = (const float*)d_in[1];
    const float* Wq   = (const float*)d_in[2];
    const float* bq   = (const float*)d_in[3];
    const float* Wk   = (const float*)d_in[4];
    const float* bk   = (const float*)d_in[5];
    const float* Wv   = (const float*)d_in[6];
    const float* bv   = (const float*)d_in[7];
    float* out = (float*)d_out;

    char* ws = (char*)d_ws;
    if (ws_size < (size_t)73433088) return;
    u16* xb   = (u16*)(ws);
    u16* wb   = (u16*)(ws + 16777216);
    u16* Qb   = (u16*)(ws + 23068672);
    u16* Kb   = (u16*)(ws + 39845888);
    u16* Vtb  = (u16*)(ws + 56623104);
    float* em = (float*)(ws + 73400320);

    cvt_all<<<11296, 256, 0, stream>>>((const float4*)x, (const float4*)Wq, (const float4*)Wk,
                                       (const float4*)Wv, (ushort4*)xb, (ushort4*)wb, mask, em);
    qkv_gemm<<<dim3(64, 8, 3), 256, 0, stream>>>(xb, wb, bq, bk, bv, em, Qb, Kb, Vtb);
    attn_kernel<<<2048, 128, 0, stream>>>(Qb, Kb, Vtb, em, out);
}

// Round 11
// 169.932 us; speedup vs baseline: 1.1564x; 1.1564x over previous
//
#include <hip/hip_runtime.h>
#include <hip/hip_bf16.h>

typedef __attribute__((ext_vector_type(4))) float f32x4;
typedef __attribute__((ext_vector_type(16))) float f32x16;
typedef __attribute__((ext_vector_type(8))) short bf16x8;
typedef __attribute__((ext_vector_type(4))) unsigned int u32x4;
typedef unsigned short u16;

#define DEV static __device__ __forceinline__

DEV u16 f2bf(float f) {
    union { float f; unsigned int u; } v; v.f = f;
    unsigned int r = v.u + 0x7FFFu + ((v.u >> 16) & 1u);
    return (u16)(r >> 16);
}

DEV unsigned int cvt_pk(float lo, float hi) {
    unsigned int r;
    asm("v_cvt_pk_bf16_f32 %0, %1, %2" : "=v"(r) : "v"(lo), "v"(hi));
    return r;
}

// v_permlane32_swap_b32 a, b: a[32..63] <-> b[0..31]
DEV void pswap(unsigned int& a, unsigned int& b) {
    asm volatile("v_permlane32_swap_b32 %0, %1" : "+v"(a), "+v"(b));
}

DEV void async16(const void* g, void* l) {
    __builtin_amdgcn_global_load_lds((const __attribute__((address_space(1))) unsigned int*)g,
                                     (__attribute__((address_space(3))) unsigned int*)l, 16, 0, 0);
}

// ---------------- fused f32 -> bf16 convert + exp-mask precompute ----------------
__global__ void cvt_all(const float4* __restrict__ x, const float4* __restrict__ wq,
                        const float4* __restrict__ wk, const float4* __restrict__ wv,
                        ushort4* __restrict__ xb, ushort4* __restrict__ wb,
                        const float* __restrict__ mask, float* __restrict__ em) {
    int bid = blockIdx.x;
    if (bid >= 11264) {
        int i = (bid - 11264) * 256 + threadIdx.x;
        em[i] = __builtin_amdgcn_exp2f(mask[i] * 1.44269504088896340736f);
        return;
    }
    const float4* s;
    ushort4* d;
    int i;
    if (bid < 8192) {
        s = x; d = xb; i = bid * 256 + threadIdx.x;
    } else {
        int r = bid - 8192;
        int wsel = r >> 10;
        s = (wsel == 0) ? wq : (wsel == 1) ? wk : wv;
        d = wb + (size_t)wsel * 262144;
        i = (r & 1023) * 256 + threadIdx.x;
    }
    float4 v = s[i];
    ushort4 o;
    o.x = f2bf(v.x); o.y = f2bf(v.y); o.z = f2bf(v.z); o.w = f2bf(v.w);
    d[i] = o;
}

// ---------------- QKV projection GEMM (double-buffered, prefetch, 1 barrier/iter) ----------------
// p=0 -> Q scaled by 0.125*log2e, [B,H,S,64]; p=1 -> K [B,H,S,64];
// p=2 -> V transposed [B,H,64,S], pre-scaled by em[b,s]
__launch_bounds__(256, 2)
__global__ void qkv_gemm(const u16* __restrict__ xb, const u16* __restrict__ wb,
                         const float* __restrict__ bq, const float* __restrict__ bk,
                         const float* __restrict__ bv, const float* __restrict__ em,
                         u16* __restrict__ Qb, u16* __restrict__ Kb, u16* __restrict__ Vtb) {
    __shared__ u16 Al[2][128 * 64];
    __shared__ u16 Bl[2][128 * 64];
    const int t = threadIdx.x, ln = t & 63, w = t >> 6;
    const int wr = w >> 1, wc = w & 1;
    const int m0 = blockIdx.x * 128, e0 = blockIdx.y * 128, p = blockIdx.z;
    const u16* Wp = wb + (size_t)p * 1048576;
    const float* bias = (p == 0) ? bq : (p == 1) ? bk : bv;

    const int srow = t >> 3, scol = (t & 7) * 8;

    f32x4 acc[4][4];
#pragma unroll
    for (int i = 0; i < 4; i++)
#pragma unroll
        for (int j = 0; j < 4; j++) acc[i][j] = (f32x4){0.f, 0.f, 0.f, 0.f};

#define G_STAGE(buf, kk)                                                              \
    {                                                                                 \
        _Pragma("unroll")                                                             \
        for (int c = 0; c < 4; c++) {                                                 \
            int r = c * 32 + srow;                                                    \
            async16(&xb[(size_t)(m0 + r) * 1024 + (kk) + scol], &Al[buf][r * 64 + scol]); \
            async16(&Wp[(size_t)(e0 + r) * 1024 + (kk) + scol], &Bl[buf][r * 64 + scol]); \
        }                                                                             \
    }

    G_STAGE(0, 0);
    __syncthreads();
    int cur = 0;
    for (int kt = 0; kt < 16; kt++) {
        if (kt < 15) G_STAGE(cur ^ 1, (kt + 1) * 64);
#pragma unroll
        for (int kc = 0; kc < 2; kc++) {
            bf16x8 a[4], bb[4];
#pragma unroll
            for (int mf = 0; mf < 4; mf++)
                a[mf] = *(const bf16x8*)&Al[cur][(wr * 64 + mf * 16 + (ln & 15)) * 64 + kc * 32 + (ln >> 4) * 8];
#pragma unroll
            for (int nf = 0; nf < 4; nf++)
                bb[nf] = *(const bf16x8*)&Bl[cur][(wc * 64 + nf * 16 + (ln & 15)) * 64 + kc * 32 + (ln >> 4) * 8];
            __builtin_amdgcn_s_setprio(1);
#pragma unroll
            for (int mf = 0; mf < 4; mf++)
#pragma unroll
                for (int nf = 0; nf < 4; nf++)
                    acc[mf][nf] = __builtin_amdgcn_mfma_f32_16x16x32_bf16(a[mf], bb[nf], acc[mf][nf], 0, 0, 0);
            __builtin_amdgcn_s_setprio(0);
        }
        __syncthreads();
        cur ^= 1;
    }
#undef G_STAGE

    const int q16 = ln & 15, g = ln >> 4;
    if (p == 2) {
#pragma unroll
        for (int nf = 0; nf < 4; nf++) {
            int e = e0 + wc * 64 + nf * 16 + q16;
            float bias_v = bias[e];
            int h = e >> 6, hd = e & 63;
#pragma unroll
            for (int mf = 0; mf < 4; mf++) {
                int m = m0 + wr * 64 + mf * 16 + g * 4;
                int b = m >> 11, s = m & 2047;
                f32x4 emv = *(const f32x4*)&em[b * 2048 + s];
                ushort4 pk;
                pk.x = f2bf((acc[mf][nf][0] + bias_v) * emv[0]);
                pk.y = f2bf((acc[mf][nf][1] + bias_v) * emv[1]);
                pk.z = f2bf((acc[mf][nf][2] + bias_v) * emv[2]);
                pk.w = f2bf((acc[mf][nf][3] + bias_v) * emv[3]);
                *(ushort4*)&Vtb[((size_t)((b * 16 + h) * 64 + hd)) * 2048 + s] = pk;
            }
        }
    } else {
        const float qscale = (p == 0) ? 0.18033688011112042f : 1.0f;
        u16* out = (p == 0) ? Qb : Kb;
#pragma unroll
        for (int nf = 0; nf < 4; nf++) {
            int e = e0 + wc * 64 + nf * 16 + q16;
            float bias_v = bias[e];
            int h = e >> 6, hd = e & 63;
#pragma unroll
            for (int mf = 0; mf < 4; mf++) {
#pragma unroll
                for (int r = 0; r < 4; r++) {
                    int m = m0 + wr * 64 + mf * 16 + g * 4 + r;
                    int b = m >> 11, s = m & 2047;
                    out[((size_t)(b * 16 + h) * 2048 + s) * 64 + hd] = f2bf((acc[mf][nf][r] + bias_v) * qscale);
                }
            }
        }
    }
}

// ---------------- fused flash attention (32x32x16 MFMA, in-register P) ----------------
// 128-thr blocks (2 waves x 64 q); K/V dbuf (32KB) + em row staged in LDS (8KB):
// the kt loop has NO global loads besides the prefetch, so the dbuf actually overlaps.
__launch_bounds__(128, 2)
__global__ void attn_kernel(const u16* __restrict__ Q, const u16* __restrict__ K,
                            const u16* __restrict__ Vt, const float* __restrict__ em,
                            float* __restrict__ out) {
    __shared__ u16 Kl[2][64 * 64];
    __shared__ u16 Vl[2][64 * 64];
    __shared__ float eml[2048];
    const int t = threadIdx.x, ln = t & 63, w = t >> 6;   // w in {0,1}
    const int ln31 = ln & 31, hi = ln >> 5, ln7 = ln & 7;

    // bijective XCD swizzle: 1024 blocks = 8 XCDs x 128
    const int bid0 = blockIdx.x;
    const int swz = (bid0 & 7) * 128 + (bid0 >> 3);
    const int qbi = swz & 15, bh = swz >> 4;
    const int b = bh >> 4, h = bh & 15;
    const int qr = qbi * 128 + w * 64;
    const size_t base = (size_t)bh * 2048 * 64;

    // Q fragments (B-operand of S^T = K·Q^T, 32x32x16): col=q=ln31, k(d)=hi*8+j
    bf16x8 aq[2][4];   // [q-tile][d-step]
#pragma unroll
    for (int qt = 0; qt < 2; qt++)
#pragma unroll
        for (int ds = 0; ds < 4; ds++)
            aq[qt][ds] = *(const bf16x8*)&Q[base + (size_t)(qr + qt * 32 + ln31) * 64 + ds * 16 + hi * 8];

    // stage this batch-row's em into LDS (8KB; b is block-constant)
    {
        const float4* src = (const float4*)&em[b * 2048];
#pragma unroll
        for (int i = 0; i < 4; i++) {
            float4 v = src[i * 128 + t];
            *(float4*)&eml[(i * 128 + t) * 4] = v;
        }
    }

    // staging: linear LDS dest, pre-swizzled global chunk (chunk c stored at c^(row&7))
    const int rbase = t >> 3;
    const int sc = (t & 7) ^ (rbase & 7);

#define A_STAGE(buf, kk)                                                                   \
    {                                                                                      \
        _Pragma("unroll")                                                                  \
        for (int i = 0; i < 4; i++) {                                                      \
            int row = i * 16 + rbase;                                                      \
            async16(&K[base + (size_t)((kk) + row) * 64 + sc * 8], &Kl[buf][(i * 128 + t) * 8]); \
            async16(&Vt[base + (size_t)row * 2048 + (kk) + sc * 8], &Vl[buf][(i * 128 + t) * 8]); \
        }                                                                                  \
    }

    f32x16 accT[2][2];   // [d-tile dt][q-tile qt]; lane: q=ln31, d=dt*32+(r&3)+8*(r>>2)+4*hi
    f32x4 lacc[2];
#pragma unroll
    for (int dt = 0; dt < 2; dt++)
#pragma unroll
        for (int qt = 0; qt < 2; qt++) accT[dt][qt] = (f32x16){};
    lacc[0] = (f32x4){0.f, 0.f, 0.f, 0.f};
    lacc[1] = (f32x4){0.f, 0.f, 0.f, 0.f};

    A_STAGE(0, 0);
    __syncthreads();
    int cur = 0;

    for (int kt = 0; kt < 32; kt++) {
        const int k0 = kt * 64;
        if (kt < 31) A_STAGE(cur ^ 1, k0 + 64);

#pragma unroll
        for (int kti = 0; kti < 2; kti++) {
            // K fragments (A-operand): row k = kti*32+ln31, d = ds*16+hi*8+j
            bf16x8 ka[4];
#pragma unroll
            for (int ds = 0; ds < 4; ds++)
                ka[ds] = *(const bf16x8*)&Kl[cur][(kti * 32 + ln31) * 64 + (((ds << 1) | hi) ^ ln7) * 8];

            // em for this lane's k rows (from LDS: broadcast reads, no vmcnt)
            f32x4 em4[4];
#pragma unroll
            for (int rf = 0; rf < 4; rf++)
                em4[rf] = *(const f32x4*)&eml[k0 + kti * 32 + rf * 8 + hi * 4];

            u32x4 pb[2][2];   // [q-tile][k-step] B-frag u32s
#pragma unroll
            for (int qt = 0; qt < 2; qt++) {
                f32x16 z = (f32x16){};
                __builtin_amdgcn_s_setprio(1);
#pragma unroll
                for (int ds = 0; ds < 4; ds++)
                    z = __builtin_amdgcn_mfma_f32_32x32x16_bf16(ka[ds], aq[qt][ds], z, 0, 0, 0);
                __builtin_amdgcn_s_setprio(0);

                // p = exp2(score); Q pre-scaled so z is already in exp2 domain
                float p[16];
#pragma unroll
                for (int i = 0; i < 16; i++) p[i] = __builtin_amdgcn_exp2f(z[i]);

                // l partial: sum p*em over lane's k rows
#pragma unroll
                for (int rf = 0; rf < 4; rf++) {
                    lacc[qt][0] += p[4 * rf + 0] * em4[rf][0];
                    lacc[qt][1] += p[4 * rf + 1] * em4[rf][1];
                    lacc[qt][2] += p[4 * rf + 2] * em4[rf][2];
                    lacc[qt][3] += p[4 * rf + 3] * em4[rf][3];
                }

                // pack to bf16 pairs: pk[rf][i] holds k = 8rf+4hi+{2i,2i+1}
                unsigned int pk00 = cvt_pk(p[0], p[1]),   pk01 = cvt_pk(p[2], p[3]);
                unsigned int pk10 = cvt_pk(p[4], p[5]),   pk11 = cvt_pk(p[6], p[7]);
                unsigned int pk20 = cvt_pk(p[8], p[9]),   pk21 = cvt_pk(p[10], p[11]);
                unsigned int pk30 = cvt_pk(p[12], p[13]), pk31 = cvt_pk(p[14], p[15]);
                // redistribute across hi-halves: B-frag k = s*16 + hi*8 + j
                pswap(pk00, pk10); pswap(pk01, pk11);   // k-step s=0
                pswap(pk20, pk30); pswap(pk21, pk31);   // k-step s=1
                pb[qt][0][0] = pk00; pb[qt][0][1] = pk01; pb[qt][0][2] = pk10; pb[qt][0][3] = pk11;
                pb[qt][1][0] = pk20; pb[qt][1][1] = pk21; pb[qt][1][2] = pk30; pb[qt][1][3] = pk31;
            }

            // ctx^T += V'^T · P^T  (V' pre-scaled by em)
            __builtin_amdgcn_s_setprio(1);
#pragma unroll
            for (int s = 0; s < 2; s++) {
#pragma unroll
                for (int dt = 0; dt < 2; dt++) {
                    bf16x8 va = *(const bf16x8*)&Vl[cur][(dt * 32 + ln31) * 64 +
                                                         ((kti * 4 + s * 2 + hi) ^ ln7) * 8];
#pragma unroll
                    for (int qt = 0; qt < 2; qt++) {
                        bf16x8 pv = *(const bf16x8*)&pb[qt][s];
                        accT[dt][qt] = __builtin_amdgcn_mfma_f32_32x32x16_bf16(va, pv, accT[dt][qt], 0, 0, 0);
                    }
                }
            }
            __builtin_amdgcn_s_setprio(0);
        }

        __syncthreads();
        cur ^= 1;
    }
#undef A_STAGE

    // epilogue: l = own partial + partner half (hi^1), then scaled f32x4 stores
#pragma unroll
    for (int qt = 0; qt < 2; qt++) {
        float l = (lacc[qt][0] + lacc[qt][1]) + (lacc[qt][2] + lacc[qt][3]);
        l += __shfl_xor(l, 32);
        float inv = 1.0f / l;
        int q = qr + qt * 32 + ln31;
#pragma unroll
        for (int dt = 0; dt < 2; dt++) {
#pragma unroll
            for (int rf = 0; rf < 4; rf++) {
                f32x4 o;
                o[0] = accT[dt][qt][4 * rf + 0] * inv;
                o[1] = accT[dt][qt][4 * rf + 1] * inv;
                o[2] = accT[dt][qt][4 * rf + 2] * inv;
                o[3] = accT[dt][qt][4 * rf + 3] * inv;
                *(f32x4*)&out[((size_t)(b * 2048 + q)) * 1024 + h * 64 + dt * 32 + rf * 8 + hi * 4] = o;
            }
        }
    }
}

extern "C" void kernel_launch(void* const* d_in, const int* in_sizes, int n_in,
                              void* d_out, int out_size, void* d_ws, size_t ws_size,
                              hipStream_t stream) {
    const float* x    = (const float*)d_in[0];
    const float* mask = (const float*)d_in[1];
    const float* Wq   = (const float*)d_in[2];
    const float* bq   = (const float*)d_in[3];
    const float* Wk   = (const float*)d_in[4];
    const float* bk   = (const float*)d_in[5];
    const float* Wv   = (const float*)d_in[6];
    const float* bv   = (const float*)d_in[7];
    float* out = (float*)d_out;

    char* ws = (char*)d_ws;
    if (ws_size < (size_t)73433088) return;
    u16* xb   = (u16*)(ws);
    u16* wb   = (u16*)(ws + 16777216);
    u16* Qb   = (u16*)(ws + 23068672);
    u16* Kb   = (u16*)(ws + 39845888);
    u16* Vtb  = (u16*)(ws + 56623104);
    float* em = (float*)(ws + 73400320);

    cvt_all<<<11296, 256, 0, stream>>>((const float4*)x, (const float4*)Wq, (const float4*)Wk,
                                       (const float4*)Wv, (ushort4*)xb, (ushort4*)wb, mask, em);
    qkv_gemm<<<dim3(64, 8, 3), 256, 0, stream>>>(xb, wb, bq, bk, bv, em, Qb, Kb, Vtb);
    attn_kernel<<<1024, 128, 0, stream>>>(Qb, Kb, Vtb, em, out);
}